// Round 1
// baseline (791.755 us; speedup 1.0000x reference)
//
#include <hip/hip_runtime.h>
#include <hip/hip_bf16.h>
#include <stdint.h>

#define NB 8192
#define DD 1024
#define HRD 512
#define HED 4096
#define HFD 2048

typedef __attribute__((ext_vector_type(8))) short bf16x8;
typedef __attribute__((ext_vector_type(4))) float f32x4;
typedef unsigned short u16;

__device__ __forceinline__ u16 f2b(float f) {
    union { float f; uint32_t i; } c; c.f = f;
    uint32_t r = c.i + 0x7FFF + ((c.i >> 16) & 1);   // RNE
    return (u16)(r >> 16);
}
__device__ __forceinline__ float b2f(u16 u) {
    union { uint32_t i; float f; } c; c.i = ((uint32_t)u) << 16; return c.f;
}

// ---------------- init ----------------
__global__ void k_init(int* cnt) { if (threadIdx.x < 2) cnt[threadIdx.x] = 0; }

// ---------------- split x into bf16 hi/lo ----------------
__global__ __launch_bounds__(256) void k_split(const float4* __restrict__ x4,
                                               ushort4* __restrict__ hi4,
                                               ushort4* __restrict__ lo4) {
    int i = blockIdx.x * 256 + threadIdx.x;
    float4 v = x4[i];
    ushort4 h, l;
    h.x = f2b(v.x); l.x = f2b(v.x - b2f(h.x));
    h.y = f2b(v.y); l.y = f2b(v.y - b2f(h.y));
    h.z = f2b(v.z); l.z = f2b(v.z - b2f(h.z));
    h.w = f2b(v.w); l.w = f2b(v.w - b2f(h.w));
    hi4[i] = h; lo4[i] = l;
}

// ---------------- transpose fp32 [R][C] -> bf16 [C][R] ----------------
__global__ __launch_bounds__(256) void k_transpose(const float* __restrict__ in,
                                                   u16* __restrict__ out, int R, int C) {
    __shared__ float s[64][65];
    int tx = threadIdx.x & 63, ty = threadIdx.x >> 6;
    int c0 = blockIdx.x * 64, r0 = blockIdx.y * 64;
#pragma unroll
    for (int j = 0; j < 16; j++) { int r = ty + j * 4; s[r][tx] = in[(size_t)(r0 + r) * C + c0 + tx]; }
    __syncthreads();
#pragma unroll
    for (int j = 0; j < 16; j++) { int c = ty + j * 4; out[(size_t)(c0 + c) * R + r0 + tx] = f2b(s[tx][c]); }
}

__global__ __launch_bounds__(256) void k_transpose_split(const float* __restrict__ in,
                                                         u16* __restrict__ ohi, u16* __restrict__ olo,
                                                         int R, int C) {
    __shared__ float s[64][65];
    int tx = threadIdx.x & 63, ty = threadIdx.x >> 6;
    int c0 = blockIdx.x * 64, r0 = blockIdx.y * 64;
#pragma unroll
    for (int j = 0; j < 16; j++) { int r = ty + j * 4; s[r][tx] = in[(size_t)(r0 + r) * C + c0 + tx]; }
    __syncthreads();
#pragma unroll
    for (int j = 0; j < 16; j++) {
        int c = ty + j * 4;
        float v = s[tx][c];
        u16 h = f2b(v);
        ohi[(size_t)(c0 + c) * R + r0 + tx] = h;
        olo[(size_t)(c0 + c) * R + r0 + tx] = f2b(v - b2f(h));
    }
}

// ---------------- LDS tile staging: 128 rows x 64 bf16, via global_load_lds ----------------
__device__ __forceinline__ void stage_tile(const char* gRowBase, long rowStrideBytes,
                                           int rowsClamp, u16* s, int tid) {
    int wave = tid >> 6, lane = tid & 63;
#pragma unroll
    for (int is = 0; is < 4; ++is) {
        int c = wave * 4 + is;                 // 1KB chunk, wave-uniform
        int row = c * 8 + (lane >> 3);
        if (row > rowsClamp) row = rowsClamp;  // clamp (duplicate data, stores masked later)
        const char* g = gRowBase + (long)row * rowStrideBytes + (lane & 7) * 16;
        __builtin_amdgcn_global_load_lds(
            (const __attribute__((address_space(1))) void*)g,
            (__attribute__((address_space(3))) void*)((char*)s + c * 1024),
            16, 0, 0);
    }
}

// ---------------- router GEMM: h = relu( (xhi+xlo) @ (Whi+Wlo)^T + b ), fp32-grade ----------------
__global__ __launch_bounds__(256) void k_router(const u16* __restrict__ Ah, const u16* __restrict__ Al,
                                                const u16* __restrict__ Bh, const u16* __restrict__ Bl,
                                                const float* __restrict__ bias, float* __restrict__ H) {
    __shared__ u16 sAh[128 * 64], sAl[128 * 64], sBh[128 * 64], sBl[128 * 64];
    int tid = threadIdx.x, lane = tid & 63, wave = tid >> 6;
    int bn = blockIdx.x, bm = blockIdx.y;
    f32x4 acc[4][4];
#pragma unroll
    for (int i = 0; i < 4; i++)
#pragma unroll
        for (int j = 0; j < 4; j++) acc[i][j] = (f32x4)0.f;
    int wm = (wave & 1) * 64, wn = (wave >> 1) * 64;
    for (int k0 = 0; k0 < DD; k0 += 64) {
        stage_tile((const char*)(Ah + (size_t)bm * 128 * DD + k0), DD * 2, 127, sAh, tid);
        stage_tile((const char*)(Al + (size_t)bm * 128 * DD + k0), DD * 2, 127, sAl, tid);
        stage_tile((const char*)(Bh + (size_t)bn * 128 * DD + k0), DD * 2, 127, sBh, tid);
        stage_tile((const char*)(Bl + (size_t)bn * 128 * DD + k0), DD * 2, 127, sBl, tid);
        __syncthreads();
#pragma unroll
        for (int kk = 0; kk < 2; kk++) {
            int kofs = kk * 64 + (lane >> 4) * 16;
            bf16x8 vbh[4], vbl[4];
#pragma unroll
            for (int ni = 0; ni < 4; ni++) {
                int rB = (wn + ni * 16 + (lane & 15)) * 128 + kofs;
                vbh[ni] = *(const bf16x8*)((const char*)sBh + rB);
                vbl[ni] = *(const bf16x8*)((const char*)sBl + rB);
            }
#pragma unroll
            for (int mi = 0; mi < 4; mi++) {
                int rA = (wm + mi * 16 + (lane & 15)) * 128 + kofs;
                bf16x8 vah = *(const bf16x8*)((const char*)sAh + rA);
                bf16x8 val = *(const bf16x8*)((const char*)sAl + rA);
#pragma unroll
                for (int ni = 0; ni < 4; ni++) {
                    acc[mi][ni] = __builtin_amdgcn_mfma_f32_16x16x32_bf16(vah, vbh[ni], acc[mi][ni], 0, 0, 0);
                    acc[mi][ni] = __builtin_amdgcn_mfma_f32_16x16x32_bf16(vah, vbl[ni], acc[mi][ni], 0, 0, 0);
                    acc[mi][ni] = __builtin_amdgcn_mfma_f32_16x16x32_bf16(val, vbh[ni], acc[mi][ni], 0, 0, 0);
                }
            }
        }
        __syncthreads();
    }
    int quad = lane >> 4, cl = lane & 15;
#pragma unroll
    for (int mi = 0; mi < 4; mi++)
#pragma unroll
        for (int r = 0; r < 4; r++) {
            int row = bm * 128 + wm + mi * 16 + quad * 4 + r;
#pragma unroll
            for (int ni = 0; ni < 4; ni++) {
                int col = bn * 128 + wn + ni * 16 + cl;
                float v = acc[mi][ni][r] + bias[col];
                H[(size_t)row * HRD + col] = fmaxf(v, 0.f);
            }
        }
}

// ---------------- router heads: fp32 dots, argmaxes, softmax weight, compaction ----------------
__global__ __launch_bounds__(256) void k_heads(const float* __restrict__ H,
                                               const float* __restrict__ Wd, const float* __restrict__ bd,
                                               const float* __restrict__ Wm, const float* __restrict__ Wl,
                                               int* __restrict__ cnt, int* __restrict__ perm,
                                               float* __restrict__ wsc, int* __restrict__ eic) {
    int lane = threadIdx.x & 63, wave = threadIdx.x >> 6;
    int r = blockIdx.x * 4 + wave;
    const float4* h4 = (const float4*)(H + (size_t)r * HRD);
    float4 v0 = h4[lane * 2], v1 = h4[lane * 2 + 1];
    float hv[8] = {v0.x, v0.y, v0.z, v0.w, v1.x, v1.y, v1.z, v1.w};
    float a[10];
#pragma unroll
    for (int t = 0; t < 10; t++) a[t] = 0.f;
    int kbase = lane * 8;
#pragma unroll
    for (int j = 0; j < 8; j++) {
        int k = kbase + j;
        float h_ = hv[j];
        float2 wd = ((const float2*)Wd)[k];
        a[0] += h_ * wd.x; a[1] += h_ * wd.y;
        float4 wm = ((const float4*)Wm)[k];
        a[2] += h_ * wm.x; a[3] += h_ * wm.y; a[4] += h_ * wm.z; a[5] += h_ * wm.w;
        float4 wl = ((const float4*)Wl)[k];
        a[6] += h_ * wl.x; a[7] += h_ * wl.y; a[8] += h_ * wl.z; a[9] += h_ * wl.w;
    }
#pragma unroll
    for (int t = 0; t < 10; t++)
#pragma unroll
        for (int off = 32; off > 0; off >>= 1) a[t] += __shfl_down(a[t], off);
    if (lane == 0) {
        float d0 = a[0] + bd[0], d1 = a[1] + bd[1];
        int primary = (d1 > d0) ? 1 : 0;                       // first-max tie-break
        float w = 1.f / (1.f + expf(-fabsf(d0 - d1)));         // softmax weight of chosen
        int mi = 0; float mv = a[2];
        if (a[3] > mv) { mv = a[3]; mi = 1; }
        if (a[4] > mv) { mv = a[4]; mi = 2; }
        if (a[5] > mv) { mv = a[5]; mi = 3; }
        int li = 0; float lv = a[6];
        if (a[7] > lv) { lv = a[7]; li = 1; }
        if (a[8] > lv) { lv = a[8]; li = 2; }
        if (a[9] > lv) { lv = a[9]; li = 3; }
        int pos;
        if (primary == 0) pos = atomicAdd(&cnt[0], 1);
        else              pos = NB - 1 - atomicAdd(&cnt[1], 1);
        perm[pos] = r; wsc[pos] = w; eic[pos] = (primary == 0) ? mi : li;
    }
}

// ---------------- gather: xin_c[i] = bf16(x[perm[i]] + emb[eic[i]]) ----------------
__global__ __launch_bounds__(256) void k_gather(const float* __restrict__ x,
                                                const float* __restrict__ op_emb,
                                                const float* __restrict__ task_emb,
                                                const int* __restrict__ perm, const int* __restrict__ eic,
                                                const int* __restrict__ cnt, u16* __restrict__ xin) {
    int lane = threadIdx.x & 63, wave = threadIdx.x >> 6;
    int i = blockIdx.x * 4 + wave;
    int n0 = cnt[0];
    int r = perm[i];
    const float* emb = ((i >= n0) ? task_emb : op_emb) + (size_t)eic[i] * DD;
    const float4* x4 = (const float4*)(x + (size_t)r * DD);
    const float4* e4 = (const float4*)emb;
    ushort4* o4 = (ushort4*)(xin + (size_t)i * DD);
#pragma unroll
    for (int j = 0; j < 4; j++) {
        int idx = lane + j * 64;
        float4 xv = x4[idx], ev = e4[idx];
        ushort4 o;
        o.x = f2b(xv.x + ev.x); o.y = f2b(xv.y + ev.y);
        o.z = f2b(xv.z + ev.z); o.w = f2b(xv.w + ev.w);
        o4[idx] = o;
    }
}

// ---------------- main bf16 GEMM (m97 structure), A[M][K] @ Bt[N][K]^T ----------------
// EPI 0: relu -> bf16 out; EPI 1: scale by wsel -> bf16 out; EPI 2: + resid, scatter fp32 out
template <int EPI>
__global__ __launch_bounds__(256) void k_gemm_bt(const u16* __restrict__ A, const u16* __restrict__ Bt,
                                                 const float* __restrict__ bias, void* __restrict__ Out,
                                                 int K, int N, const int* __restrict__ cnt, int expertSel,
                                                 const float* __restrict__ wsel, const int* __restrict__ perm,
                                                 const u16* __restrict__ resid) {
    __shared__ u16 sA[128 * 64];
    __shared__ u16 sB[128 * 64];
    int tid = threadIdx.x, lane = tid & 63, wave = tid >> 6;
    int bn = blockIdx.x, bm = blockIdx.y;
    int rowStart = 0, rowCount = NB;
    if (expertSel == 0) { rowCount = cnt[0]; }
    else if (expertSel == 1) { rowStart = cnt[0]; rowCount = NB - rowStart; }
    if (bm * 128 >= rowCount) return;
    int rcA = rowCount - bm * 128 - 1; if (rcA > 127) rcA = 127;
    f32x4 acc[4][4];
#pragma unroll
    for (int i = 0; i < 4; i++)
#pragma unroll
        for (int j = 0; j < 4; j++) acc[i][j] = (f32x4)0.f;
    int wm = (wave & 1) * 64, wn = (wave >> 1) * 64;
    const char* aBase = (const char*)(A + (size_t)(rowStart + bm * 128) * K);
    const char* bBase = (const char*)(Bt + (size_t)bn * 128 * K);
    for (int k0 = 0; k0 < K; k0 += 64) {
        stage_tile(aBase + (size_t)k0 * 2, (long)K * 2, rcA, sA, tid);
        stage_tile(bBase + (size_t)k0 * 2, (long)K * 2, 127, sB, tid);
        __syncthreads();
#pragma unroll
        for (int kk = 0; kk < 2; kk++) {
            int kofs = kk * 64 + (lane >> 4) * 16;
            bf16x8 vb[4];
#pragma unroll
            for (int ni = 0; ni < 4; ni++)
                vb[ni] = *(const bf16x8*)((const char*)sB + (wn + ni * 16 + (lane & 15)) * 128 + kofs);
#pragma unroll
            for (int mi = 0; mi < 4; mi++) {
                bf16x8 va = *(const bf16x8*)((const char*)sA + (wm + mi * 16 + (lane & 15)) * 128 + kofs);
#pragma unroll
                for (int ni = 0; ni < 4; ni++)
                    acc[mi][ni] = __builtin_amdgcn_mfma_f32_16x16x32_bf16(va, vb[ni], acc[mi][ni], 0, 0, 0);
            }
        }
        __syncthreads();
    }
    int quad = lane >> 4, cl = lane & 15;
#pragma unroll
    for (int mi = 0; mi < 4; mi++)
#pragma unroll
        for (int r = 0; r < 4; r++) {
            int lrow = bm * 128 + wm + mi * 16 + quad * 4 + r;
            if (lrow >= rowCount) continue;
            int grow = rowStart + lrow;
#pragma unroll
            for (int ni = 0; ni < 4; ni++) {
                int col = bn * 128 + wn + ni * 16 + cl;
                float v = acc[mi][ni][r] + bias[col];
                if constexpr (EPI == 0) {
                    ((u16*)Out)[(size_t)grow * N + col] = f2b(fmaxf(v, 0.f));
                } else if constexpr (EPI == 1) {
                    ((u16*)Out)[(size_t)grow * N + col] = f2b(v * wsel[grow]);
                } else {
                    v += b2f(resid[(size_t)grow * N + col]);
                    ((float*)Out)[(size_t)perm[grow] * N + col] = v;
                }
            }
        }
}

extern "C" void kernel_launch(void* const* d_in, const int* in_sizes, int n_in,
                              void* d_out, int out_size, void* d_ws, size_t ws_size,
                              hipStream_t stream) {
    const float* x      = (const float*)d_in[0];
    const float* W_r1   = (const float*)d_in[1];
    const float* b_r1   = (const float*)d_in[2];
    const float* W_dom  = (const float*)d_in[3];
    const float* b_dom  = (const float*)d_in[4];
    const float* W_mop  = (const float*)d_in[5];
    const float* W_lt   = (const float*)d_in[6];
    const float* op_emb = (const float*)d_in[7];
    const float* W_m1   = (const float*)d_in[8];
    const float* b_m1   = (const float*)d_in[9];
    const float* W_m2   = (const float*)d_in[10];
    const float* b_m2   = (const float*)d_in[11];
    const float* task_emb = (const float*)d_in[12];
    const float* W_l1   = (const float*)d_in[13];
    const float* b_l1   = (const float*)d_in[14];
    const float* W_l2   = (const float*)d_in[15];
    const float* b_l2   = (const float*)d_in[16];
    const float* W_f1   = (const float*)d_in[17];
    const float* b_f1   = (const float*)d_in[18];
    const float* W_f2   = (const float*)d_in[19];
    const float* b_f2   = (const float*)d_in[20];

    char* wsp = (char*)d_ws;
    size_t off = 0;
    auto take = [&](size_t bytes) -> char* {
        char* p = wsp + off;
        off += (bytes + 255) & ~(size_t)255;
        return p;
    };
    u16* Wr_hi = (u16*)take((size_t)HRD * DD * 2);
    u16* Wr_lo = (u16*)take((size_t)HRD * DD * 2);
    u16* Wm1t  = (u16*)take((size_t)HED * DD * 2);
    u16* Wl1t  = (u16*)take((size_t)HED * DD * 2);
    u16* Wm2t  = (u16*)take((size_t)DD * HED * 2);
    u16* Wl2t  = (u16*)take((size_t)DD * HED * 2);
    u16* Wf1t  = (u16*)take((size_t)HFD * DD * 2);
    u16* Wf2t  = (u16*)take((size_t)DD * HFD * 2);
    u16* x_hi  = (u16*)take((size_t)NB * DD * 2);
    u16* x_lo  = (u16*)take((size_t)NB * DD * 2);
    float* Hbuf = (float*)take((size_t)NB * HRD * 4);
    u16* hid   = (u16*)take((size_t)NB * HED * 2);
    int* cnt   = (int*)take(256);
    int* perm  = (int*)take(NB * 4);
    int* eic   = (int*)take(NB * 4);
    float* wsc = (float*)take(NB * 4);
    // aliases (lifetime-disjoint):
    u16* xin   = x_hi;   // gather runs after router GEMM consumed x_hi
    u16* fused = x_lo;   // L2 writes after router GEMM consumed x_lo
    u16* hid2  = Wm1t;   // F1 writes after all expert GEMMs consumed Wm1t..Wl2t (32MB contiguous)

    k_init<<<1, 64, 0, stream>>>(cnt);
    k_split<<<(NB * DD / 4) / 256, 256, 0, stream>>>((const float4*)x, (ushort4*)x_hi, (ushort4*)x_lo);
    k_transpose_split<<<dim3(HRD / 64, DD / 64), 256, 0, stream>>>(W_r1, Wr_hi, Wr_lo, DD, HRD);
    k_transpose<<<dim3(HED / 64, DD / 64), 256, 0, stream>>>(W_m1, Wm1t, DD, HED);
    k_transpose<<<dim3(HED / 64, DD / 64), 256, 0, stream>>>(W_l1, Wl1t, DD, HED);
    k_transpose<<<dim3(DD / 64, HED / 64), 256, 0, stream>>>(W_m2, Wm2t, HED, DD);
    k_transpose<<<dim3(DD / 64, HED / 64), 256, 0, stream>>>(W_l2, Wl2t, HED, DD);
    k_transpose<<<dim3(HFD / 64, DD / 64), 256, 0, stream>>>(W_f1, Wf1t, DD, HFD);
    k_transpose<<<dim3(DD / 64, HFD / 64), 256, 0, stream>>>(W_f2, Wf2t, HFD, DD);

    k_router<<<dim3(HRD / 128, NB / 128), 256, 0, stream>>>(x_hi, x_lo, Wr_hi, Wr_lo, b_r1, Hbuf);
    k_heads<<<NB / 4, 256, 0, stream>>>(Hbuf, W_dom, b_dom, W_mop, W_lt, cnt, perm, wsc, eic);
    k_gather<<<NB / 4, 256, 0, stream>>>(x, op_emb, task_emb, perm, eic, cnt, xin);

    // expert layer 1 (relu -> hid)
    k_gemm_bt<0><<<dim3(HED / 128, NB / 128), 256, 0, stream>>>(xin, Wm1t, b_m1, hid, DD, HED, cnt, 0, nullptr, nullptr, nullptr);
    k_gemm_bt<0><<<dim3(HED / 128, NB / 128), 256, 0, stream>>>(xin, Wl1t, b_l1, hid, DD, HED, cnt, 1, nullptr, nullptr, nullptr);
    // expert layer 2 (scale by routing weight -> fused)
    k_gemm_bt<1><<<dim3(DD / 128, NB / 128), 256, 0, stream>>>(hid, Wm2t, b_m2, fused, HED, DD, cnt, 0, wsc, nullptr, nullptr);
    k_gemm_bt<1><<<dim3(DD / 128, NB / 128), 256, 0, stream>>>(hid, Wl2t, b_l2, fused, HED, DD, cnt, 1, wsc, nullptr, nullptr);
    // fusion MLP
    k_gemm_bt<0><<<dim3(HFD / 128, NB / 128), 256, 0, stream>>>(fused, Wf1t, b_f1, hid2, DD, HFD, cnt, -1, nullptr, nullptr, nullptr);
    k_gemm_bt<2><<<dim3(DD / 128, NB / 128), 256, 0, stream>>>(hid2, Wf2t, b_f2, d_out, HFD, DD, cnt, -1, nullptr, perm, fused);
}

// Round 2
// 756.958 us; speedup vs baseline: 1.0460x; 1.0460x over previous
//
#include <hip/hip_runtime.h>
#include <hip/hip_bf16.h>
#include <stdint.h>

#define NB 8192
#define DD 1024
#define HRD 512
#define HED 4096
#define HFD 2048

typedef __attribute__((ext_vector_type(8))) short bf16x8;
typedef __attribute__((ext_vector_type(4))) float f32x4;
typedef unsigned short u16;

__device__ __forceinline__ u16 f2b(float f) {
    union { float f; uint32_t i; } c; c.f = f;
    uint32_t r = c.i + 0x7FFF + ((c.i >> 16) & 1);   // RNE
    return (u16)(r >> 16);
}
__device__ __forceinline__ float b2f(u16 u) {
    union { uint32_t i; float f; } c; c.i = ((uint32_t)u) << 16; return c.f;
}

// ---------------- init ----------------
__global__ void k_init(int* cnt) { if (threadIdx.x < 2) cnt[threadIdx.x] = 0; }

// ---------------- split x into bf16 hi/lo ----------------
__global__ __launch_bounds__(256) void k_split(const float4* __restrict__ x4,
                                               ushort4* __restrict__ hi4,
                                               ushort4* __restrict__ lo4) {
    int i = blockIdx.x * 256 + threadIdx.x;
    float4 v = x4[i];
    ushort4 h, l;
    h.x = f2b(v.x); l.x = f2b(v.x - b2f(h.x));
    h.y = f2b(v.y); l.y = f2b(v.y - b2f(h.y));
    h.z = f2b(v.z); l.z = f2b(v.z - b2f(h.z));
    h.w = f2b(v.w); l.w = f2b(v.w - b2f(h.w));
    hi4[i] = h; lo4[i] = l;
}

// ---------------- transpose fp32 [R][C] -> bf16 [C][R] ----------------
__global__ __launch_bounds__(256) void k_transpose(const float* __restrict__ in,
                                                   u16* __restrict__ out, int R, int C) {
    __shared__ float s[64][65];
    int tx = threadIdx.x & 63, ty = threadIdx.x >> 6;
    int c0 = blockIdx.x * 64, r0 = blockIdx.y * 64;
#pragma unroll
    for (int j = 0; j < 16; j++) { int r = ty + j * 4; s[r][tx] = in[(size_t)(r0 + r) * C + c0 + tx]; }
    __syncthreads();
#pragma unroll
    for (int j = 0; j < 16; j++) { int c = ty + j * 4; out[(size_t)(c0 + c) * R + r0 + tx] = f2b(s[tx][c]); }
}

__global__ __launch_bounds__(256) void k_transpose_split(const float* __restrict__ in,
                                                         u16* __restrict__ ohi, u16* __restrict__ olo,
                                                         int R, int C) {
    __shared__ float s[64][65];
    int tx = threadIdx.x & 63, ty = threadIdx.x >> 6;
    int c0 = blockIdx.x * 64, r0 = blockIdx.y * 64;
#pragma unroll
    for (int j = 0; j < 16; j++) { int r = ty + j * 4; s[r][tx] = in[(size_t)(r0 + r) * C + c0 + tx]; }
    __syncthreads();
#pragma unroll
    for (int j = 0; j < 16; j++) {
        int c = ty + j * 4;
        float v = s[tx][c];
        u16 h = f2b(v);
        ohi[(size_t)(c0 + c) * R + r0 + tx] = h;
        olo[(size_t)(c0 + c) * R + r0 + tx] = f2b(v - b2f(h));
    }
}

// ---------------- LDS tile staging: 128 rows x 64 bf16, via global_load_lds ----------------
__device__ __forceinline__ void stage_tile(const char* gRowBase, long rowStrideBytes,
                                           u16* s, int tid) {
    int wave = tid >> 6, lane = tid & 63;
#pragma unroll
    for (int is = 0; is < 4; ++is) {
        int c = wave * 4 + is;                 // 1KB chunk, wave-uniform
        int row = c * 8 + (lane >> 3);
        const char* g = gRowBase + (long)row * rowStrideBytes + (lane & 7) * 16;
        __builtin_amdgcn_global_load_lds(
            (const __attribute__((address_space(1))) void*)g,
            (__attribute__((address_space(3))) void*)((char*)s + c * 1024),
            16, 0, 0);
    }
}

// ---------------- router GEMM: h = relu( (xhi+xlo) @ (Whi+Wlo)^T + b ), fp32-grade ----------------
__global__ __launch_bounds__(256) void k_router(const u16* __restrict__ Ah, const u16* __restrict__ Al,
                                                const u16* __restrict__ Bh, const u16* __restrict__ Bl,
                                                const float* __restrict__ bias, float* __restrict__ H) {
    __shared__ u16 sAh[128 * 64], sAl[128 * 64], sBh[128 * 64], sBl[128 * 64];
    int tid = threadIdx.x, lane = tid & 63, wave = tid >> 6;
    int bm = blockIdx.x, bn = blockIdx.y;   // bm-fast: concurrent blocks share B-tile
    f32x4 acc[4][4];
#pragma unroll
    for (int i = 0; i < 4; i++)
#pragma unroll
        for (int j = 0; j < 4; j++) acc[i][j] = (f32x4)0.f;
    int wm = (wave & 1) * 64, wn = (wave >> 1) * 64;
    for (int k0 = 0; k0 < DD; k0 += 64) {
        stage_tile((const char*)(Ah + (size_t)bm * 128 * DD + k0), DD * 2, sAh, tid);
        stage_tile((const char*)(Al + (size_t)bm * 128 * DD + k0), DD * 2, sAl, tid);
        stage_tile((const char*)(Bh + (size_t)bn * 128 * DD + k0), DD * 2, sBh, tid);
        stage_tile((const char*)(Bl + (size_t)bn * 128 * DD + k0), DD * 2, sBl, tid);
        __syncthreads();
#pragma unroll
        for (int kk = 0; kk < 2; kk++) {
            int kofs = kk * 64 + (lane >> 4) * 16;
            bf16x8 vbh[4], vbl[4];
#pragma unroll
            for (int ni = 0; ni < 4; ni++) {
                int rB = (wn + ni * 16 + (lane & 15)) * 128 + kofs;
                vbh[ni] = *(const bf16x8*)((const char*)sBh + rB);
                vbl[ni] = *(const bf16x8*)((const char*)sBl + rB);
            }
#pragma unroll
            for (int mi = 0; mi < 4; mi++) {
                int rA = (wm + mi * 16 + (lane & 15)) * 128 + kofs;
                bf16x8 vah = *(const bf16x8*)((const char*)sAh + rA);
                bf16x8 val = *(const bf16x8*)((const char*)sAl + rA);
#pragma unroll
                for (int ni = 0; ni < 4; ni++) {
                    acc[mi][ni] = __builtin_amdgcn_mfma_f32_16x16x32_bf16(vah, vbh[ni], acc[mi][ni], 0, 0, 0);
                    acc[mi][ni] = __builtin_amdgcn_mfma_f32_16x16x32_bf16(vah, vbl[ni], acc[mi][ni], 0, 0, 0);
                    acc[mi][ni] = __builtin_amdgcn_mfma_f32_16x16x32_bf16(val, vbh[ni], acc[mi][ni], 0, 0, 0);
                }
            }
        }
        __syncthreads();
    }
    int quad = lane >> 4, cl = lane & 15;
#pragma unroll
    for (int mi = 0; mi < 4; mi++)
#pragma unroll
        for (int r = 0; r < 4; r++) {
            int row = bm * 128 + wm + mi * 16 + quad * 4 + r;
#pragma unroll
            for (int ni = 0; ni < 4; ni++) {
                int col = bn * 128 + wn + ni * 16 + cl;
                float v = acc[mi][ni][r] + bias[col];
                H[(size_t)row * HRD + col] = fmaxf(v, 0.f);
            }
        }
}

// ---------------- router heads: fp32 dots, argmaxes, softmax weight, compaction ----------------
__global__ __launch_bounds__(256) void k_heads(const float* __restrict__ H,
                                               const float* __restrict__ Wd, const float* __restrict__ bd,
                                               const float* __restrict__ Wm, const float* __restrict__ Wl,
                                               int* __restrict__ cnt, int* __restrict__ perm,
                                               float* __restrict__ wsc, int* __restrict__ eic) {
    int lane = threadIdx.x & 63, wave = threadIdx.x >> 6;
    int r = blockIdx.x * 4 + wave;
    const float4* h4 = (const float4*)(H + (size_t)r * HRD);
    float4 v0 = h4[lane * 2], v1 = h4[lane * 2 + 1];
    float hv[8] = {v0.x, v0.y, v0.z, v0.w, v1.x, v1.y, v1.z, v1.w};
    float a[10];
#pragma unroll
    for (int t = 0; t < 10; t++) a[t] = 0.f;
    int kbase = lane * 8;
#pragma unroll
    for (int j = 0; j < 8; j++) {
        int k = kbase + j;
        float h_ = hv[j];
        float2 wd = ((const float2*)Wd)[k];
        a[0] += h_ * wd.x; a[1] += h_ * wd.y;
        float4 wm = ((const float4*)Wm)[k];
        a[2] += h_ * wm.x; a[3] += h_ * wm.y; a[4] += h_ * wm.z; a[5] += h_ * wm.w;
        float4 wl = ((const float4*)Wl)[k];
        a[6] += h_ * wl.x; a[7] += h_ * wl.y; a[8] += h_ * wl.z; a[9] += h_ * wl.w;
    }
#pragma unroll
    for (int t = 0; t < 10; t++)
#pragma unroll
        for (int off = 32; off > 0; off >>= 1) a[t] += __shfl_down(a[t], off);
    if (lane == 0) {
        float d0 = a[0] + bd[0], d1 = a[1] + bd[1];
        int primary = (d1 > d0) ? 1 : 0;                       // first-max tie-break
        float w = 1.f / (1.f + expf(-fabsf(d0 - d1)));         // softmax weight of chosen
        int mi = 0; float mv = a[2];
        if (a[3] > mv) { mv = a[3]; mi = 1; }
        if (a[4] > mv) { mv = a[4]; mi = 2; }
        if (a[5] > mv) { mv = a[5]; mi = 3; }
        int li = 0; float lv = a[6];
        if (a[7] > lv) { lv = a[7]; li = 1; }
        if (a[8] > lv) { lv = a[8]; li = 2; }
        int pos;
        if (a[9] > lv) { lv = a[9]; li = 3; }
        if (primary == 0) pos = atomicAdd(&cnt[0], 1);
        else              pos = NB - 1 - atomicAdd(&cnt[1], 1);
        perm[pos] = r; wsc[pos] = w; eic[pos] = (primary == 0) ? mi : li;
    }
}

// ---------------- gather: xin_c[i] = bf16(x[perm[i]] + emb[eic[i]]) ----------------
__global__ __launch_bounds__(256) void k_gather(const float* __restrict__ x,
                                                const float* __restrict__ op_emb,
                                                const float* __restrict__ task_emb,
                                                const int* __restrict__ perm, const int* __restrict__ eic,
                                                const int* __restrict__ cnt, u16* __restrict__ xin) {
    int lane = threadIdx.x & 63, wave = threadIdx.x >> 6;
    int i = blockIdx.x * 4 + wave;
    int n0 = cnt[0];
    int r = perm[i];
    const float* emb = ((i >= n0) ? task_emb : op_emb) + (size_t)eic[i] * DD;
    const float4* x4 = (const float4*)(x + (size_t)r * DD);
    const float4* e4 = (const float4*)emb;
    ushort4* o4 = (ushort4*)(xin + (size_t)i * DD);
#pragma unroll
    for (int j = 0; j < 4; j++) {
        int idx = lane + j * 64;
        float4 xv = x4[idx], ev = e4[idx];
        ushort4 o;
        o.x = f2b(xv.x + ev.x); o.y = f2b(xv.y + ev.y);
        o.z = f2b(xv.z + ev.z); o.w = f2b(xv.w + ev.w);
        o4[idx] = o;
    }
}

// ---------------- fused dual-expert GEMM (m97 structure), A[M][K] @ Bt[N][K]^T ----------------
// grid y-dim (or x if BMFAST) = 65 tiles: t<=tb -> math weights on tile t, else lang on tile t-1;
// boundary tile computed twice, stores row-masked. EPI 0: relu->bf16; EPI 1: *wsel ->bf16.
template <int EPI, bool BMFAST>
__global__ __launch_bounds__(256) void k_gemm_dual(const u16* __restrict__ A,
                                                   const u16* __restrict__ Btm, const u16* __restrict__ Btl,
                                                   const float* __restrict__ biasm, const float* __restrict__ biasl,
                                                   u16* __restrict__ Out, int K, int N,
                                                   const int* __restrict__ cnt, const float* __restrict__ wsel) {
    __shared__ u16 sA[128 * 64];
    __shared__ u16 sB[128 * 64];
    int tid = threadIdx.x, lane = tid & 63, wave = tid >> 6;
    int bn, t;
    if (BMFAST) { t = blockIdx.x; bn = blockIdx.y; } else { bn = blockIdx.x; t = blockIdx.y; }
    int n0 = cnt[0];
    int tb = n0 >> 7;
    bool isMath = (t <= tb) && (t < 64);
    int tile = isMath ? t : (t - 1);
    int storeLo, storeHi;
    if (isMath) { storeLo = tile * 128; storeHi = n0 < storeLo + 128 ? n0 : storeLo + 128; }
    else        { storeHi = tile * 128 + 128; storeLo = n0 > tile * 128 ? n0 : tile * 128; }
    if (storeLo >= storeHi) return;   // uniform across block
    const u16* Bt = isMath ? Btm : Btl;
    const float* bias = isMath ? biasm : biasl;
    f32x4 acc[4][4];
#pragma unroll
    for (int i = 0; i < 4; i++)
#pragma unroll
        for (int j = 0; j < 4; j++) acc[i][j] = (f32x4)0.f;
    int wm = (wave & 1) * 64, wn = (wave >> 1) * 64;
    const char* aBase = (const char*)(A + (size_t)tile * 128 * K);
    const char* bBase = (const char*)(Bt + (size_t)bn * 128 * K);
    for (int k0 = 0; k0 < K; k0 += 64) {
        stage_tile(aBase + (size_t)k0 * 2, (long)K * 2, sA, tid);
        stage_tile(bBase + (size_t)k0 * 2, (long)K * 2, sB, tid);
        __syncthreads();
#pragma unroll
        for (int kk = 0; kk < 2; kk++) {
            int kofs = kk * 64 + (lane >> 4) * 16;
            bf16x8 vb[4];
#pragma unroll
            for (int ni = 0; ni < 4; ni++)
                vb[ni] = *(const bf16x8*)((const char*)sB + (wn + ni * 16 + (lane & 15)) * 128 + kofs);
#pragma unroll
            for (int mi = 0; mi < 4; mi++) {
                bf16x8 va = *(const bf16x8*)((const char*)sA + (wm + mi * 16 + (lane & 15)) * 128 + kofs);
#pragma unroll
                for (int ni = 0; ni < 4; ni++)
                    acc[mi][ni] = __builtin_amdgcn_mfma_f32_16x16x32_bf16(va, vb[ni], acc[mi][ni], 0, 0, 0);
            }
        }
        __syncthreads();
    }
    int quad = lane >> 4, cl = lane & 15;
#pragma unroll
    for (int mi = 0; mi < 4; mi++)
#pragma unroll
        for (int r = 0; r < 4; r++) {
            int grow = tile * 128 + wm + mi * 16 + quad * 4 + r;
            if (grow < storeLo || grow >= storeHi) continue;
#pragma unroll
            for (int ni = 0; ni < 4; ni++) {
                int col = bn * 128 + wn + ni * 16 + cl;
                float v = acc[mi][ni][r] + bias[col];
                if constexpr (EPI == 0) {
                    Out[(size_t)grow * N + col] = f2b(fmaxf(v, 0.f));
                } else {
                    Out[(size_t)grow * N + col] = f2b(v * wsel[grow]);
                }
            }
        }
}

// ---------------- plain GEMM for fusion MLP ----------------
// EPI 0: relu -> bf16 out; EPI 2: + resid, scatter fp32 out via perm
template <int EPI, bool BMFAST>
__global__ __launch_bounds__(256) void k_gemm_bt(const u16* __restrict__ A, const u16* __restrict__ Bt,
                                                 const float* __restrict__ bias, void* __restrict__ Out,
                                                 int K, int N,
                                                 const int* __restrict__ perm, const u16* __restrict__ resid) {
    __shared__ u16 sA[128 * 64];
    __shared__ u16 sB[128 * 64];
    int tid = threadIdx.x, lane = tid & 63, wave = tid >> 6;
    int bn, bm;
    if (BMFAST) { bm = blockIdx.x; bn = blockIdx.y; } else { bn = blockIdx.x; bm = blockIdx.y; }
    f32x4 acc[4][4];
#pragma unroll
    for (int i = 0; i < 4; i++)
#pragma unroll
        for (int j = 0; j < 4; j++) acc[i][j] = (f32x4)0.f;
    int wm = (wave & 1) * 64, wn = (wave >> 1) * 64;
    const char* aBase = (const char*)(A + (size_t)bm * 128 * K);
    const char* bBase = (const char*)(Bt + (size_t)bn * 128 * K);
    for (int k0 = 0; k0 < K; k0 += 64) {
        stage_tile(aBase + (size_t)k0 * 2, (long)K * 2, sA, tid);
        stage_tile(bBase + (size_t)k0 * 2, (long)K * 2, sB, tid);
        __syncthreads();
#pragma unroll
        for (int kk = 0; kk < 2; kk++) {
            int kofs = kk * 64 + (lane >> 4) * 16;
            bf16x8 vb[4];
#pragma unroll
            for (int ni = 0; ni < 4; ni++)
                vb[ni] = *(const bf16x8*)((const char*)sB + (wn + ni * 16 + (lane & 15)) * 128 + kofs);
#pragma unroll
            for (int mi = 0; mi < 4; mi++) {
                bf16x8 va = *(const bf16x8*)((const char*)sA + (wm + mi * 16 + (lane & 15)) * 128 + kofs);
#pragma unroll
                for (int ni = 0; ni < 4; ni++)
                    acc[mi][ni] = __builtin_amdgcn_mfma_f32_16x16x32_bf16(va, vb[ni], acc[mi][ni], 0, 0, 0);
            }
        }
        __syncthreads();
    }
    int quad = lane >> 4, cl = lane & 15;
#pragma unroll
    for (int mi = 0; mi < 4; mi++)
#pragma unroll
        for (int r = 0; r < 4; r++) {
            int grow = bm * 128 + wm + mi * 16 + quad * 4 + r;
#pragma unroll
            for (int ni = 0; ni < 4; ni++) {
                int col = bn * 128 + wn + ni * 16 + cl;
                float v = acc[mi][ni][r] + bias[col];
                if constexpr (EPI == 0) {
                    ((u16*)Out)[(size_t)grow * N + col] = f2b(fmaxf(v, 0.f));
                } else {
                    v += b2f(resid[(size_t)grow * N + col]);
                    ((float*)Out)[(size_t)perm[grow] * N + col] = v;
                }
            }
        }
}

extern "C" void kernel_launch(void* const* d_in, const int* in_sizes, int n_in,
                              void* d_out, int out_size, void* d_ws, size_t ws_size,
                              hipStream_t stream) {
    const float* x      = (const float*)d_in[0];
    const float* W_r1   = (const float*)d_in[1];
    const float* b_r1   = (const float*)d_in[2];
    const float* W_dom  = (const float*)d_in[3];
    const float* b_dom  = (const float*)d_in[4];
    const float* W_mop  = (const float*)d_in[5];
    const float* W_lt   = (const float*)d_in[6];
    const float* op_emb = (const float*)d_in[7];
    const float* W_m1   = (const float*)d_in[8];
    const float* b_m1   = (const float*)d_in[9];
    const float* W_m2   = (const float*)d_in[10];
    const float* b_m2   = (const float*)d_in[11];
    const float* task_emb = (const float*)d_in[12];
    const float* W_l1   = (const float*)d_in[13];
    const float* b_l1   = (const float*)d_in[14];
    const float* W_l2   = (const float*)d_in[15];
    const float* b_l2   = (const float*)d_in[16];
    const float* W_f1   = (const float*)d_in[17];
    const float* b_f1   = (const float*)d_in[18];
    const float* W_f2   = (const float*)d_in[19];
    const float* b_f2   = (const float*)d_in[20];

    char* wsp = (char*)d_ws;
    size_t off = 0;
    auto take = [&](size_t bytes) -> char* {
        char* p = wsp + off;
        off += (bytes + 255) & ~(size_t)255;
        return p;
    };
    u16* Wr_hi = (u16*)take((size_t)HRD * DD * 2);
    u16* Wr_lo = (u16*)take((size_t)HRD * DD * 2);
    u16* Wm1t  = (u16*)take((size_t)HED * DD * 2);
    u16* Wl1t  = (u16*)take((size_t)HED * DD * 2);
    u16* Wm2t  = (u16*)take((size_t)DD * HED * 2);
    u16* Wl2t  = (u16*)take((size_t)DD * HED * 2);
    u16* Wf1t  = (u16*)take((size_t)HFD * DD * 2);
    u16* Wf2t  = (u16*)take((size_t)DD * HFD * 2);
    u16* x_hi  = (u16*)take((size_t)NB * DD * 2);
    u16* x_lo  = (u16*)take((size_t)NB * DD * 2);
    float* Hbuf = (float*)take((size_t)NB * HRD * 4);
    u16* hid   = (u16*)take((size_t)NB * HED * 2);
    int* cnt   = (int*)take(256);
    int* perm  = (int*)take(NB * 4);
    int* eic   = (int*)take(NB * 4);
    float* wsc = (float*)take(NB * 4);
    // aliases (lifetime-disjoint):
    u16* xin   = x_hi;   // gather runs after router GEMM consumed x_hi
    u16* fused = x_lo;   // L2 writes after router GEMM consumed x_lo
    u16* hid2  = Wm1t;   // F1 writes after all expert GEMMs consumed Wm1t..Wl2t (32MB contiguous)

    k_init<<<1, 64, 0, stream>>>(cnt);
    k_split<<<(NB * DD / 4) / 256, 256, 0, stream>>>((const float4*)x, (ushort4*)x_hi, (ushort4*)x_lo);
    k_transpose_split<<<dim3(HRD / 64, DD / 64), 256, 0, stream>>>(W_r1, Wr_hi, Wr_lo, DD, HRD);
    k_transpose<<<dim3(HED / 64, DD / 64), 256, 0, stream>>>(W_m1, Wm1t, DD, HED);
    k_transpose<<<dim3(HED / 64, DD / 64), 256, 0, stream>>>(W_l1, Wl1t, DD, HED);
    k_transpose<<<dim3(DD / 64, HED / 64), 256, 0, stream>>>(W_m2, Wm2t, HED, DD);
    k_transpose<<<dim3(DD / 64, HED / 64), 256, 0, stream>>>(W_l2, Wl2t, HED, DD);
    k_transpose<<<dim3(HFD / 64, DD / 64), 256, 0, stream>>>(W_f1, Wf1t, DD, HFD);
    k_transpose<<<dim3(DD / 64, HFD / 64), 256, 0, stream>>>(W_f2, Wf2t, HFD, DD);

    k_router<<<dim3(NB / 128, HRD / 128), 256, 0, stream>>>(x_hi, x_lo, Wr_hi, Wr_lo, b_r1, Hbuf);
    k_heads<<<NB / 4, 256, 0, stream>>>(Hbuf, W_dom, b_dom, W_mop, W_lt, cnt, perm, wsc, eic);
    k_gather<<<NB / 4, 256, 0, stream>>>(x, op_emb, task_emb, perm, eic, cnt, xin);

    // expert layer 1 fused (relu -> hid): grid y = 65 row-tiles (boundary double-pass)
    k_gemm_dual<0, false><<<dim3(HED / 128, NB / 128 + 1), 256, 0, stream>>>(
        xin, Wm1t, Wl1t, b_m1, b_l1, hid, DD, HED, cnt, nullptr);
    // expert layer 2 fused (scale by routing weight -> fused): bm-fast for B-tile locality
    k_gemm_dual<1, true><<<dim3(NB / 128 + 1, DD / 128), 256, 0, stream>>>(
        hid, Wm2t, Wl2t, b_m2, b_l2, fused, HED, DD, cnt, wsc);
    // fusion MLP
    k_gemm_bt<0, false><<<dim3(HFD / 128, NB / 128), 256, 0, stream>>>(
        fused, Wf1t, b_f1, hid2, DD, HFD, nullptr, nullptr);
    k_gemm_bt<2, true><<<dim3(NB / 128, DD / 128), 256, 0, stream>>>(
        hid2, Wf2t, b_f2, d_out, HFD, DD, perm, fused);
}